// Round 4
// baseline (523.702 us; speedup 1.0000x reference)
//
#include <hip/hip_runtime.h>

// DenseGrid trilinear interpolation, MI355X.
// R6: fine two-level sort + simple gather main kernel.
// R5 lesson: LDS-staging the codebook serialized the kernel (512 blocks, 1/CU,
// occupancy 25%, VALUBusy 10%). Once rec is finely sorted, the gathers are
// L1/L2-hits by themselves -- so run the R3-style gather kernel (32768 blocks,
// no codebook LDS, no per-bin barriers) on the sorted stream instead.
//  - Pass A: coarse 512-bin block-aggregated counting sort (proven cheap).
//  - Pass B: per-coarse-bin in-LDS in-place subsort, key = (y-in-tile, x>>4)
//    -> 256 keys; instantaneous gather footprint ~9 KB.
//  - k_main6: one 576-thread block per 64 sorted points, 9 threads/point,
//    global vf2 gathers (cache-hot), nt store to out[original idx].
//    Bijective XCD swizzle so each XCD walks a contiguous sorted span.
// Per-point math is the identical fma chain everywhere -> absmax unchanged.
// Fallback to the R2 single-kernel path if workspace is too small.

constexpr int RES  = 128;
constexpr int NBA  = 512;           // coarse bins: (iz0<<2)|(iy0>>5)
constexpr int TPM  = 576;           // 9 threads/point, 64 pts/block
constexpr int PPB  = 64;
constexpr int SUB_CAP = 8160;       // LDS rec cache per coarse bin (mean 4096)

constexpr int HIST_CHUNK = 1024;
constexpr int SCAT_CHUNK = 16384;

typedef float vf2 __attribute__((ext_vector_type(2)));
typedef float vf4 __attribute__((ext_vector_type(4)));

struct Xf {
    float m00, m01, m02, m10, m11, m12, m20, m21, m22;
    float tx, ty, tz;
};

__device__ __forceinline__ Xf load_xf(const float* __restrict__ tr) {
    Xf X;
    const float a = tr[0], b = tr[1],  c = tr[2];
    const float d = tr[4], e = tr[5],  g = tr[6];
    const float h = tr[8], i = tr[9],  j = tr[10];
    X.tx = tr[3]; X.ty = tr[7]; X.tz = tr[11];
    const float det = a*(e*j - g*i) - b*(d*j - g*h) + c*(d*i - e*h);
    const float rd  = 1.0f / det;
    X.m00 = (e*j - g*i) * rd; X.m01 = (c*i - b*j) * rd; X.m02 = (b*g - c*e) * rd;
    X.m10 = (g*h - d*j) * rd; X.m11 = (a*j - c*h) * rd; X.m12 = (c*d - a*g) * rd;
    X.m20 = (d*i - e*h) * rd; X.m21 = (b*h - a*i) * rd; X.m22 = (a*e - b*d) * rd;
    return X;
}

// Explicit fma chain: identical across all kernels (bin assignment must match).
__device__ __forceinline__ float qcoord(float m0, float m1, float m2,
                                        float x, float y, float z) {
    return __fmaf_rn(m0, x, __fmaf_rn(m1, y, m2 * z)) * (float)(RES - 1);
}

__device__ __forceinline__ int clamp_idx(float q) {
    return min(max((int)floorf(q), 0), RES - 1);
}

__device__ __forceinline__ int coarse_key(float qy, float qz) {
    return (clamp_idx(qz) << 2) | (clamp_idx(qy) >> 5);
}

// ---------------------------------------------------------------- pass A ----
__global__ __launch_bounds__(256)
void k_zero(unsigned* __restrict__ histA) {
    const int i = blockIdx.x * 256 + threadIdx.x;
    if (i < NBA) histA[i] = 0u;
}

__global__ __launch_bounds__(256)
void k_histA(const float* __restrict__ pts, const float* __restrict__ tr,
             unsigned* __restrict__ histA, int npts)
{
    __shared__ unsigned sh[NBA];
    const int t = threadIdx.x;
    for (int b = t; b < NBA; b += 256) sh[b] = 0u;
    __syncthreads();
    const Xf X = load_xf(tr);
    const int base = blockIdx.x * HIST_CHUNK;
    #pragma unroll
    for (int i = 0; i < HIST_CHUNK / 256; ++i) {
        const int p = base + t + i * 256;
        if (p < npts) {
            const float x = pts[p*3 + 0] - X.tx;
            const float y = pts[p*3 + 1] - X.ty;
            const float z = pts[p*3 + 2] - X.tz;
            const float qy = qcoord(X.m10, X.m11, X.m12, x, y, z);
            const float qz = qcoord(X.m20, X.m21, X.m22, x, y, z);
            atomicAdd(&sh[coarse_key(qy, qz)], 1u);
        }
    }
    __syncthreads();
    for (int b = t; b < NBA; b += 256) {
        const unsigned c = sh[b];
        if (c) atomicAdd(&histA[b], c);
    }
}

__global__ __launch_bounds__(NBA)
void k_scanA(const unsigned* __restrict__ histA,
             unsigned* __restrict__ baseA, unsigned* __restrict__ cursorA)
{
    __shared__ unsigned s[NBA];
    const int t = threadIdx.x;
    const unsigned my = histA[t];
    s[t] = my;
    __syncthreads();
    for (int off = 1; off < NBA; off <<= 1) {
        const unsigned v = (t >= off) ? s[t - off] : 0u;
        __syncthreads();
        s[t] += v;
        __syncthreads();
    }
    baseA[t]   = s[t] - my;
    cursorA[t] = s[t] - my;
}

__global__ __launch_bounds__(256)
void k_scatA(const float* __restrict__ pts, const float* __restrict__ tr,
             unsigned* __restrict__ cursorA, vf4* __restrict__ rec, int npts)
{
    __shared__ unsigned shist[NBA], sbase[NBA], scur[NBA];
    const int t = threadIdx.x;
    for (int b = t; b < NBA; b += 256) { shist[b] = 0u; scur[b] = 0u; }
    __syncthreads();
    const Xf X = load_xf(tr);
    const int base = blockIdx.x * SCAT_CHUNK;
    for (int i = 0; i < SCAT_CHUNK / 256; ++i) {
        const int p = base + t + i * 256;
        if (p < npts) {
            const float x = pts[p*3 + 0] - X.tx;
            const float y = pts[p*3 + 1] - X.ty;
            const float z = pts[p*3 + 2] - X.tz;
            const float qy = qcoord(X.m10, X.m11, X.m12, x, y, z);
            const float qz = qcoord(X.m20, X.m21, X.m22, x, y, z);
            atomicAdd(&shist[coarse_key(qy, qz)], 1u);
        }
    }
    __syncthreads();
    for (int b = t; b < NBA; b += 256)
        sbase[b] = shist[b] ? atomicAdd(&cursorA[b], shist[b]) : 0u;
    __syncthreads();
    for (int i = 0; i < SCAT_CHUNK / 256; ++i) {
        const int p = base + t + i * 256;
        if (p < npts) {
            const float x = pts[p*3 + 0] - X.tx;
            const float y = pts[p*3 + 1] - X.ty;
            const float z = pts[p*3 + 2] - X.tz;
            const float qx = qcoord(X.m00, X.m01, X.m02, x, y, z);
            const float qy = qcoord(X.m10, X.m11, X.m12, x, y, z);
            const float qz = qcoord(X.m20, X.m21, X.m22, x, y, z);
            const int bn = coarse_key(qy, qz);
            const unsigned r = atomicAdd(&scur[bn], 1u);
            unsigned pos = sbase[bn] + r;
            if (pos >= (unsigned)npts) pos = (unsigned)npts - 1u;  // insurance
            vf4 v; v.x = qx; v.y = qy; v.z = qz; v.w = __int_as_float(p);
            rec[pos] = v;
        }
    }
}

// ---------------------------------------------------------------- pass B ----
// One block per coarse bin: in-LDS, in-place subsort to (y-in-tile, x>>4)
// order -> 256 keys. Order affects only performance, never correctness, so
// an overflowed bin (never expected at ~60 sigma) just skips sorting.
__global__ __launch_bounds__(1024)
void k_subsort(vf4* __restrict__ rec, const unsigned* __restrict__ histA,
               const unsigned* __restrict__ baseA)
{
    const int cbn = blockIdx.x;
    const int t = threadIdx.x;
    const unsigned n = histA[cbn];
    const unsigned b0 = baseA[cbn];
    const int ybase = (cbn & 3) << 5;

    if (n == 0u || n > (unsigned)SUB_CAP) return;

    __shared__ vf4 c[SUB_CAP];
    __shared__ unsigned h[256], cur[256];
    for (int k = t; k < 256; k += 1024) h[k] = 0u;
    __syncthreads();

    for (unsigned i = t; i < n; i += 1024) {
        const vf4 v = rec[b0 + i];
        c[i] = v;
        const int ky = min(max(clamp_idx(v.y) - ybase, 0), 31);
        const int kx = clamp_idx(v.x) >> 4;
        atomicAdd(&h[(ky << 3) | kx], 1u);
    }
    __syncthreads();
    if (t == 0) {
        unsigned run = 0u;
        for (int k = 0; k < 256; ++k) { cur[k] = run; run += h[k]; }
    }
    __syncthreads();
    for (unsigned i = t; i < n; i += 1024) {
        const vf4 v = c[i];
        const int ky = min(max(clamp_idx(v.y) - ybase, 0), 31);
        const int kx = clamp_idx(v.x) >> 4;
        const unsigned pos = atomicAdd(&cur[(ky << 3) | kx], 1u);
        rec[b0 + pos] = v;          // block-exclusive range: no false sharing
    }
}

// ---------------------------------------------------------------- k_main ----
__global__ __launch_bounds__(TPM)
void k_main6(const vf4* __restrict__ rec, const float* __restrict__ cb,
             float* __restrict__ out, int npts, int nwg)
{
    // Bijective XCD swizzle: blocks resident on one XCD (blockIdx % 8 under
    // round-robin dispatch) process a CONTIGUOUS span of the sorted stream,
    // so each XCD's private L2 walks a contiguous codebook window.
    const int bid = blockIdx.x;
    const int q = nwg >> 3, r = nwg & 7;
    const int xcd = bid & 7, lin = bid >> 3;
    const int blk = (xcd < r ? xcd * (q + 1) : r * (q + 1) + (xcd - r) * q) + lin;

    __shared__ vf4 srec[PPB];
    const int t = threadIdx.x;
    const int g0 = blk * PPB;
    if (t < PPB) {
        const int g = g0 + t;
        if (g < npts) srec[t] = __builtin_nontemporal_load(&rec[g]);
    }
    __syncthreads();

    const int pl = t / 9;
    const int f  = t - pl * 9;
    const int p  = g0 + pl;
    if (p >= npts) return;

    const vf4 rr = srec[pl];
    const float qx = rr.x, qy = rr.y, qz = rr.z;
    const int idx = __float_as_int(rr.w);

    const float fx = floorf(qx), fy = floorf(qy), fz = floorf(qz);
    const float wx1 = qx - fx, wy1 = qy - fy, wz1 = qz - fz;
    const float wx0 = 1.0f - wx1, wy0 = 1.0f - wy1, wz0 = 1.0f - wz1;
    const int ix0 = clamp_idx(qx); const int ix1 = min(ix0 + 1, RES - 1);
    const int iy0 = clamp_idx(qy); const int iy1 = min(iy0 + 1, RES - 1);
    const int iz0 = clamp_idx(qz); const int iz1 = min(iz0 + 1, RES - 1);

    int   ro[8];
    float w[8];
    #pragma unroll
    for (int k = 0; k < 8; ++k) {
        const int dx = k & 1, dy = (k >> 1) & 1, dz = k >> 2;
        ro[k] = (dx ? ix1 : ix0) + ((dy ? iy1 : iy0) << 7) + ((dz ? iz1 : iz0) << 14);
        w[k]  = (dx ? wx1 : wx0) * (dy ? wy1 : wy0) * (dz ? wz1 : wz0);
    }

    // Cache-hot gathers: sorted order makes the live window ~9 KB.
    const float* cbf = cb + 2 * f;
    vf2 v[8];
    #pragma unroll
    for (int k = 0; k < 8; ++k)
        v[k] = *reinterpret_cast<const vf2*>(cbf + (size_t)ro[k] * 18);

    float ax = 0.0f, ay = 0.0f;
    #pragma unroll
    for (int k = 0; k < 8; ++k) { ax += v[k].x * w[k]; ay += v[k].y * w[k]; }

    vf2 o; o.x = ax; o.y = ay;
    __builtin_nontemporal_store(o, reinterpret_cast<vf2*>(out + (size_t)idx * 18 + 2 * f));
}

// ---------------- R2 fallback (used only if workspace is too small) ----------
__global__ __launch_bounds__(TPM)
void dense_grid_trilerp(const float* __restrict__ pts,
                        const float* __restrict__ cb,
                        const float* __restrict__ tr,
                        float* __restrict__ out,
                        int npts)
{
    __shared__ float spts[PPB * 3];
    if (threadIdx.x < PPB * 3) {
        int g = blockIdx.x * (PPB * 3) + threadIdx.x;
        spts[threadIdx.x] = (g < npts * 3) ? __builtin_nontemporal_load(&pts[g]) : 0.0f;
    }
    __syncthreads();

    const int pl = threadIdx.x / 9;
    const int f  = threadIdx.x - pl * 9;
    const int p  = blockIdx.x * PPB + pl;
    if (p >= npts) return;

    const Xf X = load_xf(tr);
    const float x = spts[pl*3 + 0] - X.tx;
    const float y = spts[pl*3 + 1] - X.ty;
    const float z = spts[pl*3 + 2] - X.tz;
    const float qx = qcoord(X.m00, X.m01, X.m02, x, y, z);
    const float qy = qcoord(X.m10, X.m11, X.m12, x, y, z);
    const float qz = qcoord(X.m20, X.m21, X.m22, x, y, z);

    const float fx = floorf(qx), fy = floorf(qy), fz = floorf(qz);
    const float wx1 = qx - fx, wy1 = qy - fy, wz1 = qz - fz;
    const float wx0 = 1.0f - wx1, wy0 = 1.0f - wy1, wz0 = 1.0f - wz1;
    const int ix0 = clamp_idx(qx); const int ix1 = min(ix0 + 1, RES - 1);
    const int iy0 = clamp_idx(qy); const int iy1 = min(iy0 + 1, RES - 1);
    const int iz0 = clamp_idx(qz); const int iz1 = min(iz0 + 1, RES - 1);

    int   ro[8];
    float w[8];
    #pragma unroll
    for (int k = 0; k < 8; ++k) {
        const int dx = k & 1, dy = (k >> 1) & 1, dz = k >> 2;
        ro[k] = (dx ? ix1 : ix0) + ((dy ? iy1 : iy0) << 7) + ((dz ? iz1 : iz0) << 14);
        w[k]  = (dx ? wx1 : wx0) * (dy ? wy1 : wy0) * (dz ? wz1 : wz0);
    }

    const float* cbf = cb + 2 * f;
    vf2 v[8];
    #pragma unroll
    for (int k = 0; k < 8; ++k)
        v[k] = *reinterpret_cast<const vf2*>(cbf + (size_t)ro[k] * 18);

    float ax = 0.0f, ay = 0.0f;
    #pragma unroll
    for (int k = 0; k < 8; ++k) { ax += v[k].x * w[k]; ay += v[k].y * w[k]; }

    vf2 o; o.x = ax; o.y = ay;
    __builtin_nontemporal_store(o, reinterpret_cast<vf2*>(out + p * 18 + 2 * f));
}

extern "C" void kernel_launch(void* const* d_in, const int* in_sizes, int n_in,
                              void* d_out, int out_size, void* d_ws, size_t ws_size,
                              hipStream_t stream) {
    const float* pts = (const float*)d_in[0];   // [4*524288, 3] f32
    const float* cb  = (const float*)d_in[1];   // [128^3, 18] f32
    const float* tr  = (const float*)d_in[2];   // [4,4] f32
    float* out = (float*)d_out;                 // [4*524288, 18] f32

    const int npts = in_sizes[0] / 3;

    // meta: histA(512) baseA(512) cursorA(512) = 6144 B (256-aligned)
    const size_t meta = (size_t)(NBA * 3) * sizeof(unsigned);
    const size_t need = meta + (size_t)npts * 16;
    if (d_ws == nullptr || ws_size < need || npts <= 0) {
        const int blocks = (npts + PPB - 1) / PPB;
        dense_grid_trilerp<<<blocks, TPM, 0, stream>>>(pts, cb, tr, out, npts);
        return;
    }

    unsigned* histA   = (unsigned*)d_ws;
    unsigned* baseA   = histA + NBA;
    unsigned* cursorA = baseA + NBA;
    vf4* rec = (vf4*)((char*)d_ws + meta);

    const int nwg = (npts + PPB - 1) / PPB;
    k_zero<<<(NBA + 255) / 256, 256, 0, stream>>>(histA);
    k_histA<<<(npts + HIST_CHUNK - 1) / HIST_CHUNK, 256, 0, stream>>>(pts, tr, histA, npts);
    k_scanA<<<1, NBA, 0, stream>>>(histA, baseA, cursorA);
    k_scatA<<<(npts + SCAT_CHUNK - 1) / SCAT_CHUNK, 256, 0, stream>>>(pts, tr, cursorA, rec, npts);
    k_subsort<<<NBA, 1024, 0, stream>>>(rec, histA, baseA);
    k_main6<<<nwg, TPM, 0, stream>>>(rec, cb, out, npts, nwg);
}